// Round 8
// baseline (362.397 us; speedup 1.0000x reference)
//
#include <hip/hip_runtime.h>
#include <math.h>

#define NUM_TAGS 20000
#define BATCH 64
#define H4 1024
#define HD 256
#define NT1 20001   // NUM_TAGS + 1

__device__ __forceinline__ float gelu_exact(float x) {
    return 0.5f * x * (1.0f + erff(x * 0.7071067811865476f));
}

// 4-byte-aligned float4 (rows can be misaligned: ld=20001)
struct F4 { float x, y, z, w; };

// ---- async global->LDS (gfx950). LDS dest = wave-uniform base + lane*size.
typedef const __attribute__((address_space(1))) void* gp_t;
typedef __attribute__((address_space(3))) void* lp_t;
__device__ __forceinline__ void async_ld4(const float* g, float* lds_base) {
    __builtin_amdgcn_global_load_lds((gp_t)g, (lp_t)lds_base, 4, 0, 0);
}
__device__ __forceinline__ void async_ld16(const float* g, float* lds_base) {
    __builtin_amdgcn_global_load_lds((gp_t)g, (lp_t)lds_base, 16, 0, 0);
}

// ---------- fused: scatter(dedup) + LN1 stats + LN1 apply, all in LDS -------
__global__ __launch_bounds__(1024) void k_ln1_fused(const int* __restrict__ tags,
                                                    const float* __restrict__ fc,
                                                    const float* __restrict__ lng,
                                                    const float* __restrict__ lnb,
                                                    float* __restrict__ y) {
    __shared__ int hist[NUM_TAGS];
    __shared__ float ls[16], ls2[16], smu, srs;
    const int b = blockIdx.x, tid = threadIdx.x;

    for (int t = tid; t < NUM_TAGS; t += 1024) hist[t] = 0;
    __syncthreads();

    if (tid < 128) {
        const int* tp = tags + ((size_t)(b * 128 + tid) << 4);
        int t[16];
#pragma unroll
        for (int i = 0; i < 16; ++i) t[i] = tp[i];
#pragma unroll
        for (int i = 0; i < 16; ++i) {
            bool dup = false;
            for (int j = 0; j < i; ++j) dup = dup || (t[j] == t[i]);
            if (!dup) atomicAdd(&hist[t[i]], 1);
        }
    }
    __syncthreads();

    float s = 0.f, s2 = 0.f;
    for (int t = tid; t < NUM_TAGS; t += 1024) {
        float v = (float)hist[t];
        s += v; s2 += v * v;
    }
#pragma unroll
    for (int off = 32; off > 0; off >>= 1) {
        s  += __shfl_down(s, off);
        s2 += __shfl_down(s2, off);
    }
    int wave = tid >> 6;
    if ((tid & 63) == 0) { ls[wave] = s; ls2[wave] = s2; }
    __syncthreads();
    if (tid == 0) {
        float S = 0.f, S2 = 0.f;
#pragma unroll
        for (int i = 0; i < 16; ++i) { S += ls[i]; S2 += ls2[i]; }
        float mu = S / (float)NUM_TAGS;
        float var = S2 / (float)NUM_TAGS - mu * mu;
        smu = mu;
        srs = rsqrtf(var + 1e-5f);
    }
    __syncthreads();
    float mu = smu, rs = srs;

    float* yrow = y + (size_t)b * NT1;
    if (tid == 0) yrow[0] = fc[b] * 0.01f;
    for (int t = tid; t < NUM_TAGS; t += 1024) {
        float v = (float)hist[t];
        yrow[1 + t] = (v - mu) * rs * lng[t] + lnb[t];
    }
}

// ------------- 2-wave 8x8-register-tile split-K GEMM, 64x128 tiles ----------
// P[(bx*gridDim.y+ky)][64][128] = A[64, kslice] @ W[kslice, 128cols]
// 128 thr = 2 waves: tn=tid&15 (cols tn*4..+3 and 64+tn*4..+3), tb=tid>>4
// (rows tb*8..+7).  8x8 acc per thread: 16 A + 16 W b128 reads per chunk
// for 512 FMAs (1:16 LDS:FMA).
// BK=8, FOUR LDS buffers (24 KB), depth-2 prefetch, counted vmcnt.
// *** Buffer-count proof (round-7 bug): max wave skew = fast wave issuing
// chunk c+2 while slowest wave still READS chunk c-1 (one barrier/iter).
// Need (c+2)-(c-1)=3 != 0 mod NBUF -> NBUF=4 safe, NBUF=3 RACES. ***
// A LDS layout: granule (4dw = one row's k-quad) at slot q holds source
// granule g(q) = q ^ ((q>>3)&3) (involution; swizzle on DMA SOURCE, m173/G21).
// Read slot q = k4*64 + tb*8 + (i^tb3): (q>>3)&3 = tb3, so granule low bits
// (i^tb3)^tb3 = i -> a4[i] = A[row tb*8+i] -> accumulate into acc[i]
// (round-6 bug: a second XOR on the acc index re-permuted rows).
// Bank check, fixed i: 4 tb-groups/wave read banks 4*(i^tb3): distinct,
// 16-lane broadcast each -> conflict-free. W read split-col tn*4 / 64+tn*4
// -> 2-way distinct-addr (free, m136).
// Loads/thread/chunk L: A-al 1 ld16, A-mis 4 ld4; W-al 2 ld16, W-mis 8 ld4.
// Last K-slice may be short: nchunk = min(kpb, K-kstart)/8 (must be %8).
// launch_bounds(128,2): do NOT raise min-waves (round-1: forcing waves
// clamped VGPR to 64 -> 94 MB scratch spill).
template <int AMIS, int WMIS>
__global__ __launch_bounds__(128, 2) void k_gemm(const float* __restrict__ A, int lda,
                                                 const float* __restrict__ W, int ldw,
                                                 float* __restrict__ P,
                                                 int N, int K, int kpb) {
    __shared__ __align__(16) float As[4][512];    // swizzled [k4][row][klo]
    __shared__ __align__(16) float Ws[4][1024];   // [kk][col] : kk*128 + col
    const int tid = threadIdx.x;
    const int wid = tid >> 6;
    const int tn = tid & 15, tb = tid >> 4;
    const int tb3 = tb & 3;
    const int n0 = blockIdx.x * 128;
    const int kstart = blockIdx.y * kpb;
    const int krem = K - kstart;
    const int nchunk = (kpb < krem ? kpb : krem) >> 3;

    float acc[8][8];
#pragma unroll
    for (int i = 0; i < 8; ++i)
#pragma unroll
        for (int j = 0; j < 8; ++j) acc[i][j] = 0.f;

    // ---- issue chunk c into buffer buf (async DMA) ----
    auto issue = [&](int buf, int c) {
        int k0 = kstart + c * 8;
        // ---- A tile: 64 rows x 8 k = 512 dwords = 128 granules, swizzled.
        if (AMIS) {
            // 4 ld4: dword slot qd=j*128+tid; granule q=qd>>2 -> source
            // granule g = q ^ ((q>>3)&3); row=g&63, k4=g>>6, klo=qd&3.
#pragma unroll
            for (int j = 0; j < 4; ++j) {
                int qd = j * 128 + tid;
                int q = qd >> 2, klo = qd & 3;
                int g = q ^ ((q >> 3) & 3);
                int row = g & 63, k4 = g >> 6;
                async_ld4(A + (size_t)row * lda + k0 + k4 * 4 + klo,
                          &As[buf][j * 128 + wid * 64]);
            }
        } else {
            // 1 ld16: granule slot q=tid -> g = q ^ ((q>>3)&3)
            int g = tid ^ ((tid >> 3) & 3);
            int row = g & 63, k4 = g >> 6;
            async_ld16(A + (size_t)row * lda + k0 + k4 * 4, &As[buf][wid * 256]);
        }
        // ---- W tile: 8 k x 128 cols = 1024 dwords (linear layout)
        if (WMIS) {
            // 8 ld4: dword qd=j*128+tid -> kk=qd>>7, cc=qd&127 (col clamped)
#pragma unroll
            for (int j = 0; j < 8; ++j) {
                int qd = j * 128 + tid;
                int kk = qd >> 7, cc = qd & 127;
                async_ld4(W + (size_t)(k0 + kk) * ldw + min(n0 + cc, N - 1),
                          &Ws[buf][j * 128 + wid * 64]);
            }
        } else {
            // 2 ld16: granule q=j*128+tid -> kk=q>>5, c4=q&31
#pragma unroll
            for (int j = 0; j < 2; ++j) {
                int q = j * 128 + tid;
                int kk = q >> 5, c4 = q & 31;
                async_ld16(W + (size_t)(k0 + kk) * ldw + n0 + c4 * 4,
                           &Ws[buf][j * 512 + wid * 256]);
            }
        }
    };

    const int L = (AMIS ? 4 : 1) + (WMIS ? 8 : 2);   // loads/thread/chunk

    issue(0, 0);
    if (nchunk > 1) issue(1, 1);

    for (int c = 0; c < nchunk; ++c) {
        if (c + 2 < nchunk) issue((c + 2) & 3, c + 2);
        // Counted wait: own chunk-c loads retired; up to 2 chunks stay in
        // flight across the barrier. (L is compile-time per instantiation.)
        int ahead = nchunk - 1 - c;
        if (ahead >= 2) {
            if (L == 6)       asm volatile("s_waitcnt vmcnt(12)" ::: "memory");
            else if (L == 3)  asm volatile("s_waitcnt vmcnt(6)"  ::: "memory");
            else              asm volatile("s_waitcnt vmcnt(18)" ::: "memory");
        } else if (ahead == 1) {
            if (L == 6)       asm volatile("s_waitcnt vmcnt(6)"  ::: "memory");
            else if (L == 3)  asm volatile("s_waitcnt vmcnt(3)"  ::: "memory");
            else              asm volatile("s_waitcnt vmcnt(9)"  ::: "memory");
        } else {
            asm volatile("s_waitcnt vmcnt(0)" ::: "memory");
        }
        __builtin_amdgcn_s_barrier();          // all waves' chunk-c loads landed
        asm volatile("" ::: "memory");         // no LDS access hoisted above

        const float* Ab = As[c & 3];
        const float* Wb = Ws[c & 3];
        __builtin_amdgcn_s_setprio(1);
#pragma unroll
        for (int k4 = 0; k4 < 2; ++k4) {
            float4 a4[8];
#pragma unroll
            for (int i = 0; i < 8; ++i)
                a4[i] = *(const float4*)&Ab[k4 * 256 + tb * 32 + ((i ^ tb3) << 2)];
            // a4[i] holds A[row = tb*8 + i][k4*4 .. +3]  (see header comment)
#pragma unroll
            for (int kl = 0; kl < 4; ++kl) {
                const float4 w0 = *(const float4*)&Wb[(k4 * 4 + kl) * 128 + tn * 4];
                const float4 w1 = *(const float4*)&Wb[(k4 * 4 + kl) * 128 + 64 + tn * 4];
#pragma unroll
                for (int i = 0; i < 8; ++i) {
                    float av = (kl == 0) ? a4[i].x : (kl == 1) ? a4[i].y
                             : (kl == 2) ? a4[i].z : a4[i].w;
                    acc[i][0] = fmaf(av, w0.x, acc[i][0]);
                    acc[i][1] = fmaf(av, w0.y, acc[i][1]);
                    acc[i][2] = fmaf(av, w0.z, acc[i][2]);
                    acc[i][3] = fmaf(av, w0.w, acc[i][3]);
                    acc[i][4] = fmaf(av, w1.x, acc[i][4]);
                    acc[i][5] = fmaf(av, w1.y, acc[i][5]);
                    acc[i][6] = fmaf(av, w1.z, acc[i][6]);
                    acc[i][7] = fmaf(av, w1.w, acc[i][7]);
                }
            }
        }
        __builtin_amdgcn_s_setprio(0);
        asm volatile("" ::: "memory");         // no LDS access sunk below
    }

    float* Pp = P + ((size_t)blockIdx.x * gridDim.y + blockIdx.y) * 8192;
#pragma unroll
    for (int i = 0; i < 8; ++i) {
        int row = tb * 8 + i;
        float4 v0 = {acc[i][0], acc[i][1], acc[i][2], acc[i][3]};
        float4 v1 = {acc[i][4], acc[i][5], acc[i][6], acc[i][7]};
        *(float4*)&Pp[row * 128 + tn * 4]      = v0;
        *(float4*)&Pp[row * 128 + 64 + tn * 4] = v1;
    }
}

// ---------------- reduce partials + bias (+gelu) ---------------------------
template <bool GELU>
__global__ __launch_bounds__(256) void k_reduce(const float* __restrict__ P, int KS,
                                                const float* __restrict__ bias,
                                                float* __restrict__ out, int ldo, int N) {
    int b = blockIdx.y;
    int n = blockIdx.x * 256 + threadIdx.x;
    if (n >= N) return;
    int nb = n >> 7, col = n & 127;
    const float* p = P + (size_t)nb * KS * 8192 + b * 128 + col;
    float s0 = 0.f, s1 = 0.f, s2 = 0.f, s3 = 0.f;
    int k = 0;
    for (; k + 3 < KS; k += 4) {
        s0 += p[(size_t)(k + 0) * 8192];
        s1 += p[(size_t)(k + 1) * 8192];
        s2 += p[(size_t)(k + 2) * 8192];
        s3 += p[(size_t)(k + 3) * 8192];
    }
    for (; k < KS; ++k) s0 += p[(size_t)k * 8192];
    float s = (s0 + s1) + (s2 + s3) + bias[n];
    if (GELU) s = gelu_exact(s);
    out[(size_t)b * ldo + n] = s;
}

// ------- fused: reduce GEMM1 partials + bias + rank1(fc) + gelu + LN2 ------
__global__ __launch_bounds__(1024) void k_red_ln2(const float* __restrict__ P, int KS,
                                                  const float* __restrict__ bias,
                                                  const float* __restrict__ r1row,
                                                  const float* __restrict__ fc,
                                                  const float* __restrict__ lng,
                                                  const float* __restrict__ lnb,
                                                  float* __restrict__ h2) {
    const int b = blockIdx.x, n = threadIdx.x;
    int nb = n >> 7, col = n & 127;
    const float* p = P + (size_t)nb * KS * 8192 + b * 128 + col;
    float s0 = 0.f, s1 = 0.f, s2v = 0.f, s3 = 0.f;
    int k = 0;
    for (; k + 3 < KS; k += 4) {
        s0  += p[(size_t)(k + 0) * 8192];
        s1  += p[(size_t)(k + 1) * 8192];
        s2v += p[(size_t)(k + 2) * 8192];
        s3  += p[(size_t)(k + 3) * 8192];
    }
    for (; k < KS; ++k) s0 += p[(size_t)k * 8192];
    float v = (s0 + s1) + (s2v + s3) + bias[n] + fc[b] * 0.01f * r1row[n];
    v = gelu_exact(v);

    float s = v, s2 = v * v;
#pragma unroll
    for (int off = 32; off > 0; off >>= 1) {
        s  += __shfl_down(s, off);
        s2 += __shfl_down(s2, off);
    }
    __shared__ float ls[16], ls2[16], smu, srs;
    int wave = n >> 6;
    if ((n & 63) == 0) { ls[wave] = s; ls2[wave] = s2; }
    __syncthreads();
    if (n == 0) {
        float S = 0.f, S2 = 0.f;
#pragma unroll
        for (int i = 0; i < 16; ++i) { S += ls[i]; S2 += ls2[i]; }
        float mu = S / (float)H4;
        float var = S2 / (float)H4 - mu * mu;
        smu = mu;
        srs = rsqrtf(var + 1e-5f);
    }
    __syncthreads();
    h2[(size_t)b * H4 + n] = (v - smu) * srs * lng[n] + lnb[n];
}

// ---------------- vectorized reduce (bias only, no gelu) for wide N --------
__global__ __launch_bounds__(256) void k_reduce_v4(const float* __restrict__ P, int KS,
                                                   const float* __restrict__ bias,
                                                   float* __restrict__ out, int ldo, int N) {
    int b = blockIdx.y;
    int n = (blockIdx.x * 256 + threadIdx.x) * 4;
    if (n >= N) return;
    int nb = n >> 7, col = n & 127;
    const float* p = P + (size_t)nb * KS * 8192 + b * 128 + col;
    if (n + 3 < N) {
        float sx = 0.f, sy = 0.f, sz = 0.f, sw = 0.f;
        for (int k = 0; k < KS; ++k) {
            float4 v = *(const float4*)&p[(size_t)k * 8192];
            sx += v.x; sy += v.y; sz += v.z; sw += v.w;
        }
        F4 bi = *(const F4*)&bias[n];
        F4 r = {sx + bi.x, sy + bi.y, sz + bi.z, sw + bi.w};
        *(F4*)&out[(size_t)b * ldo + n] = r;   // ldo odd -> 4B-aligned store
    } else {
        for (int j = 0; n + j < N; ++j) {
            float s = 0.f;
            for (int k = 0; k < KS; ++k) s += p[(size_t)k * 8192 + j];
            out[(size_t)b * ldo + n + j] = s + bias[n + j];
        }
    }
}

// ---------------- launch ----------------
extern "C" void kernel_launch(void* const* d_in, const int* in_sizes, int n_in,
                              void* d_out, int out_size, void* d_ws, size_t ws_size,
                              hipStream_t stream) {
    (void)in_sizes; (void)n_in; (void)out_size;
    const int*   tags  = (const int*)d_in[0];
    const float* fc    = (const float*)d_in[1];
    const float* ln_g  = (const float*)d_in[2];
    const float* ln_b  = (const float*)d_in[3];
    const float* w1    = (const float*)d_in[4];
    const float* b1    = (const float*)d_in[5];
    const float* ln2_g = (const float*)d_in[6];
    const float* ln2_b = (const float*)d_in[7];
    const float* we1   = (const float*)d_in[8];
    const float* be1   = (const float*)d_in[9];
    const float* we2   = (const float*)d_in[10];
    const float* be2   = (const float*)d_in[11];
    const float* wd1   = (const float*)d_in[12];
    const float* bd1   = (const float*)d_in[13];
    const float* wd2   = (const float*)d_in[14];
    const float* bd2   = (const float*)d_in[15];

    float* out = (float*)d_out;
    float* y   = out;                              // 64*20001
    float* enc = out + (size_t)BATCH * NT1;        // 64*256
    float* dec = enc + BATCH * HD;                 // 64*20001

    char* ws = (char*)d_ws;
    size_t off = 0;
    float* h2     = (float*)(ws + off); off += (size_t)BATCH * H4 * 4;
    float* g2     = (float*)(ws + off); off += (size_t)BATCH * H4 * 4;
    float* dd     = (float*)(ws + off); off += (size_t)BATCH * H4 * 4;
    float* arena  = (float*)(ws + off);
    size_t avail  = (ws_size > off) ? (ws_size - off) : 0;

    // split-K tiers (ws_size constant across calls -> deterministic).
    // kpb1=128 -> 157 slices -> arena 41.2 MB; GEMM5 KS5=8 -> 41.2 MB.
    const size_t MB = 1024 * 1024;
    int kpb1, KS5;
    if (avail >= 45 * MB)      { kpb1 = 128; KS5 = 8; }
    else if (avail >= 33 * MB) { kpb1 = 256; KS5 = 4; }
    else                       { kpb1 = 320; KS5 = 2; }
    int KS1  = (20000 + kpb1 - 1) / kpb1;   // 157 / 79 / 63 (tails %8 == 0)
    int kpb5 = H4 / KS5;

    // fused: scatter + LN1 stats + LN1 apply (LDS histogram)
    k_ln1_fused<<<64, 1024, 0, stream>>>(tags, fc, ln_g, ln_b, y);

    // GEMM1: yn[64,20000] @ w1[1:,1024]  (A misaligned: lda=20001)
    k_gemm<1, 0><<<dim3(8, KS1), 128, 0, stream>>>(y + 1, NT1, w1 + H4, H4,
                                                   arena, H4, 20000, kpb1);
    k_red_ln2<<<64, 1024, 0, stream>>>(arena, KS1, b1, w1, fc, ln2_g, ln2_b, h2);

    // GEMM2: h2 @ we1[1024,1024]
    k_gemm<0, 0><<<dim3(8, 64), 128, 0, stream>>>(h2, H4, we1, H4, arena, H4, 1024, 16);
    k_reduce<true><<<dim3(4, 64), 256, 0, stream>>>(arena, 64, be1, g2, H4, H4);

    // GEMM3: g2 @ we2[1024,256]
    k_gemm<0, 0><<<dim3(2, 64), 128, 0, stream>>>(g2, H4, we2, HD, arena, HD, 1024, 16);
    k_reduce<false><<<dim3(1, 64), 256, 0, stream>>>(arena, 64, be2, enc, HD, HD);

    // GEMM4: enc @ wd1[256,1024]
    k_gemm<0, 0><<<dim3(8, 16), 128, 0, stream>>>(enc, HD, wd1, H4, arena, H4, 256, 16);
    k_reduce<true><<<dim3(4, 64), 256, 0, stream>>>(arena, 16, bd1, dd, H4, H4);

    // GEMM5: dd @ wd2[1024,20001]  (odd ldw -> W misaligned)
    k_gemm<0, 1><<<dim3(157, KS5), 128, 0, stream>>>(dd, H4, wd2, NT1,
                                                     arena, NT1, H4, kpb5);
    k_reduce_v4<<<dim3(20, 64), 256, 0, stream>>>(arena, KS5, bd2, dec, NT1, NT1);
}